// Round 1
// baseline (314.096 us; speedup 1.0000x reference)
//
#include <hip/hip_runtime.h>
#include <hip/hip_bf16.h>

// Detect head: fused 1x1-conv (bf16 MFMA GEMM) + YOLO box decode.
// Level 0: x0[8,256,64,64], W0[1548,256]  -> out rows [0, 73728)  per batch
// Level 1: x1[8,512,32,32], W1[1548,512]  -> out rows [73728, 92160) per batch
// out: [8, 92160, 86] fp32

typedef __attribute__((ext_vector_type(8))) short short8;
typedef __attribute__((ext_vector_type(4))) short short4v;
typedef __attribute__((ext_vector_type(4))) float f32x4;

__device__ __forceinline__ unsigned short f2bf(float f) {
    union { float f; unsigned u; } c; c.f = f;
    return (unsigned short)((c.u + 0x7fffu + ((c.u >> 16) & 1u)) >> 16);  // RTNE
}
__device__ __forceinline__ float sigm(float v) {
    return 1.0f / (1.0f + __expf(-v));
}

#define OUT_CH 1548
#define NCHN   86
#define BPB    7925760   // per-batch output elements = 92160*86

__global__ __launch_bounds__(256, 1) void detect_fused(
    const float* __restrict__ x0, const float* __restrict__ x1,
    const float* __restrict__ W0, const float* __restrict__ b0,
    const float* __restrict__ W1, const float* __restrict__ b1,
    float* __restrict__ out)
{
    constexpr int BM = 128, BN = 128, BK = 32;
    // +8 pad (16B) keeps row pitch 80B -> ds_read_b128 frag loads ~2-way (free)
    __shared__ unsigned short sA[BM][BK + 8];
    __shared__ unsigned short sB[BN][BK + 8];

    const int mtile = blockIdx.x;
    const bool lvl1 = (mtile >= 256);
    const float* __restrict__ X    = lvl1 ? x1 : x0;
    const float* __restrict__ W    = lvl1 ? W1 : W0;
    const float* __restrict__ bias = lvl1 ? b1 : b0;
    const int C   = lvl1 ? 512 : 256;
    const int GG  = lvl1 ? 1024 : 4096;
    const int Gsh = lvl1 ? 5 : 6;           // log2(G)
    const float sxy     = lvl1 ? 1.1f : 1.2f;
    const float sxy_off = (sxy - 1.0f) * 0.5f;
    const float sf      = lvl1 ? 16.0f : 8.0f;
    // anchor sizes in original units (exp(v) * (w/s) * s == exp(v) * w)
    const float aw0 = lvl1 ? 30.f : 10.f, aw1v = lvl1 ? 62.f : 16.f, aw2v = lvl1 ? 59.f : 33.f;
    const float ah0 = lvl1 ? 61.f : 13.f, ah1v = lvl1 ? 45.f : 30.f, ah2v = lvl1 ? 119.f : 23.f;

    const int tloc = lvl1 ? (mtile - 256) : mtile;
    const int b  = tloc >> (lvl1 ? 3 : 5);               // tiles per batch: 8 / 32
    const int p0 = (tloc & ((lvl1 ? 8 : 32) - 1)) * BM;  // pixel offset in level grid
    const int n0 = blockIdx.y * BN;                      // out-channel offset

    const int tid  = threadIdx.x;
    const int lane = tid & 63;
    const int wid  = tid >> 6;
    const int wm = wid >> 1, wn = wid & 1;   // wave -> 64x64 quadrant

    f32x4 acc[4][4];
    #pragma unroll
    for (int i = 0; i < 4; ++i)
        #pragma unroll
        for (int j = 0; j < 4; ++j)
            acc[i][j] = f32x4{0.f, 0.f, 0.f, 0.f};

    // staging decomposition
    const int am  = tid & 127;   // pixel within tile
    const int akg = tid >> 7;    // k half (0/1): k in [akg*16, akg*16+16)
    const int bn_ = tid >> 3;    // 0..31
    const int bkq = tid & 7;     // k quad: 4 floats at k = bkq*4

    const int KT = C / BK;
    for (int kt = 0; kt < KT; ++kt) {
        const int k0 = kt * BK;
        // ---- stage A: x tile [BM pixels][BK ch], fp32->bf16 on the fly ----
        {
            short8 pk0, pk1;
            #pragma unroll
            for (int kk = 0; kk < 8; ++kk)
                pk0[kk] = (short)f2bf(X[(size_t)(b * C + k0 + akg * 16 + kk) * GG + p0 + am]);
            #pragma unroll
            for (int kk = 0; kk < 8; ++kk)
                pk1[kk] = (short)f2bf(X[(size_t)(b * C + k0 + akg * 16 + 8 + kk) * GG + p0 + am]);
            *(short8*)&sA[am][akg * 16]     = pk0;
            *(short8*)&sA[am][akg * 16 + 8] = pk1;
        }
        // ---- stage B: W tile [BN outch][BK inch] (W is [1548][C] row-major) ----
        #pragma unroll
        for (int pp = 0; pp < 4; ++pp) {
            const int n  = pp * 32 + bn_;
            const int gn = n0 + n;
            short4v pv = short4v{0, 0, 0, 0};
            if (gn < OUT_CH) {
                const float4 f = *(const float4*)&W[(size_t)gn * C + k0 + bkq * 4];
                pv[0] = (short)f2bf(f.x); pv[1] = (short)f2bf(f.y);
                pv[2] = (short)f2bf(f.z); pv[3] = (short)f2bf(f.w);
            }
            *(short4v*)&sB[n][bkq * 4] = pv;
        }
        __syncthreads();
        // ---- fragments + MFMA ----
        {
            const int kb = (lane >> 4) * 8;   // A/B: k = (lane>>4)*8 + j
            const int lr = lane & 15;         // A row / B col
            short8 af[4], bf[4];
            #pragma unroll
            for (int i = 0; i < 4; ++i) af[i] = *(const short8*)&sA[wm * 64 + i * 16 + lr][kb];
            #pragma unroll
            for (int j = 0; j < 4; ++j) bf[j] = *(const short8*)&sB[wn * 64 + j * 16 + lr][kb];
            #pragma unroll
            for (int i = 0; i < 4; ++i)
                #pragma unroll
                for (int j = 0; j < 4; ++j)
                    acc[i][j] = __builtin_amdgcn_mfma_f32_16x16x32_bf16(af[i], bf[j], acc[i][j], 0, 0, 0);
        }
        __syncthreads();
    }

    // ---- epilogue: bias + decode + scatter ----
    // C/D layout (verified m89/m91): col(N) = lane&15, row(M) = (lane>>4)*4 + reg
    const int lr = lane & 15;
    const int rq = (lane >> 4) * 4;
    const int lvloff = lvl1 ? 73728 : 0;
    #pragma unroll
    for (int j = 0; j < 4; ++j) {
        const int o = n0 + wn * 64 + j * 16 + lr;
        if (o >= OUT_CH) continue;
        const int a  = o / NCHN;
        const int ch = o - a * NCHN;
        const float bv = bias[o];
        const int shp  = a / 6;
        const int angi = a - shp * 6;
        const float aw = (shp == 0) ? aw0 : (shp == 1) ? aw1v : aw2v;
        const float ah = (shp == 0) ? ah0 : (shp == 1) ? ah1v : ah2v;
        const float aa = (angi == 0) ? -1.04719755119659775f :
                         (angi == 1) ? -0.52359877559829887f :
                         (angi == 2) ?  0.0f :
                         (angi == 3) ?  0.52359877559829887f :
                         (angi == 4) ?  1.04719755119659775f :
                                        1.57079632679489662f;
        const size_t obase = (size_t)b * BPB + ((size_t)(lvloff + a * GG)) * NCHN + ch;
        #pragma unroll
        for (int i = 0; i < 4; ++i) {
            #pragma unroll
            for (int r = 0; r < 4; ++r) {
                const int p = p0 + wm * 64 + i * 16 + rq + r;
                const float v = acc[i][j][r] + bv;
                float res;
                if (ch == 0)      res = (sigm(v) * sxy - sxy_off + (float)(p & ((1 << Gsh) - 1))) * sf;
                else if (ch == 1) res = (sigm(v) * sxy - sxy_off + (float)(p >> Gsh)) * sf;
                else if (ch == 2) res = __expf(v) * aw;
                else if (ch == 3) res = __expf(v) * ah;
                else if (ch == 4) res = v + aa;
                else              res = sigm(v);
                out[obase + (size_t)p * NCHN] = res;
            }
        }
    }
}

extern "C" void kernel_launch(void* const* d_in, const int* in_sizes, int n_in,
                              void* d_out, int out_size, void* d_ws, size_t ws_size,
                              hipStream_t stream) {
    const float* x0 = (const float*)d_in[0];
    const float* x1 = (const float*)d_in[1];
    const float* W0 = (const float*)d_in[2];
    const float* b0 = (const float*)d_in[3];
    const float* W1 = (const float*)d_in[4];
    const float* b1 = (const float*)d_in[5];
    float* out = (float*)d_out;

    // level0: 32768 px / 128 = 256 M-tiles; level1: 8192/128 = 64 -> 320 total
    // N: ceil(1548/128) = 13
    dim3 grid(320, 13, 1);
    dim3 block(256, 1, 1);
    hipLaunchKernelGGL(detect_fused, grid, block, 0, stream,
                       x0, x1, W0, b0, W1, b1, out);
}

// Round 2
// 265.080 us; speedup vs baseline: 1.1849x; 1.1849x over previous
//
#include <hip/hip_runtime.h>
#include <hip/hip_bf16.h>

// Detect head: prep (fp32->bf16 convert + x transpose) then fused MFMA GEMM + decode.
// Level 0: x0[8,256,64,64], W0[1548,256]  -> out rows [0, 73728)  per batch
// Level 1: x1[8,512,32,32], W1[1548,512]  -> out rows [73728, 92160) per batch
// out: [8, 92160, 86] fp32

typedef __attribute__((ext_vector_type(8))) short short8;
typedef __attribute__((ext_vector_type(4))) short short4v;
typedef __attribute__((ext_vector_type(4))) float f32x4;
typedef unsigned int u32;

__device__ __forceinline__ unsigned short f2bf(float f) {
    union { float f; unsigned u; } c; c.f = f;
    return (unsigned short)((c.u + 0x7fffu + ((c.u >> 16) & 1u)) >> 16);  // RTNE
}
__device__ __forceinline__ float sigm(float v) {
    return 1.0f / (1.0f + __expf(-v));
}
__device__ __forceinline__ void gload16(const void* g, void* l) {
    __builtin_amdgcn_global_load_lds(
        (const __attribute__((address_space(1))) u32*)g,
        (__attribute__((address_space(3))) u32*)l, 16, 0, 0);
}

#define OUT_CH 1548
#define NCHN   86
#define BPB    7925760   // per-batch output elements = 92160*86

// ---------------- prep kernels ----------------

__global__ void conv_w_kernel(const float* __restrict__ W, unsigned short* __restrict__ Wb, int n4) {
    int i = blockIdx.x * blockDim.x + threadIdx.x;
    if (i >= n4) return;
    const float4 f = ((const float4*)W)[i];
    short4v v;
    v[0] = (short)f2bf(f.x); v[1] = (short)f2bf(f.y);
    v[2] = (short)f2bf(f.z); v[3] = (short)f2bf(f.w);
    ((short4v*)Wb)[i] = v;
}

// x [B][C][GG] fp32 -> Xb [B][GG][C] bf16 (64x64 LDS tile transpose)
__global__ void transpose_x_kernel(const float* __restrict__ X, unsigned short* __restrict__ Xb,
                                   int C, int GG) {
    __shared__ float sT[64][65];
    const int p0 = blockIdx.x * 64;
    const int c0 = blockIdx.y * 64;
    const int b  = blockIdx.z;
    const int tid = threadIdx.x;
    const float* src = X + ((size_t)b * C + c0) * GG + p0;
    const int rc = tid >> 4;           // base c row
    const int cp = (tid & 15) * 4;     // pixel within tile (float4)
    #pragma unroll
    for (int rr = 0; rr < 4; ++rr) {
        const int c = rc + rr * 16;
        const float4 f = *(const float4*)&src[(size_t)c * GG + cp];
        sT[c][cp + 0] = f.x; sT[c][cp + 1] = f.y;
        sT[c][cp + 2] = f.z; sT[c][cp + 3] = f.w;
    }
    __syncthreads();
    const int p  = tid >> 2;           // pixel row 0..63
    const int cg = (tid & 3) * 16;     // channel group
    unsigned short u[16];
    #pragma unroll
    for (int k = 0; k < 16; ++k) u[k] = f2bf(sT[cg + k][p]);
    unsigned short* dst = Xb + ((size_t)b * GG + p0 + p) * C + c0 + cg;
    *(short8*)dst       = *(const short8*)&u[0];
    *(short8*)(dst + 8) = *(const short8*)&u[8];
}

// ---------------- main GEMM + decode ----------------

__global__ __launch_bounds__(256) void detect_gemm(
    const unsigned short* __restrict__ Xb0, const unsigned short* __restrict__ Xb1,
    const unsigned short* __restrict__ Wb0, const unsigned short* __restrict__ Wb1,
    const float* __restrict__ b0, const float* __restrict__ b1,
    float* __restrict__ out)
{
    // 128x128 tile, BK=64; linear LDS (global_load_lds) + XOR-swizzled source/read
    __shared__ __attribute__((aligned(128))) unsigned short sA[128 * 64];
    __shared__ __attribute__((aligned(128))) unsigned short sB[128 * 64];

    // XCD-grouping swizzle: 4160 = 8 * 520 blocks; all 13 N-tiles of an M-tile
    // land on the same XCD, temporally adjacent -> L2 merges partial out lines.
    const int bid   = blockIdx.x;
    const int v     = (bid & 7) * 520 + (bid >> 3);
    const int mtile = v / 13;
    const int ntile = v - mtile * 13;

    const bool lvl1 = (mtile >= 256);
    const unsigned short* __restrict__ Xb = lvl1 ? Xb1 : Xb0;
    const unsigned short* __restrict__ Wb = lvl1 ? Wb1 : Wb0;
    const float* __restrict__ bias = lvl1 ? b1 : b0;
    const int C   = lvl1 ? 512 : 256;
    const int GG  = lvl1 ? 1024 : 4096;
    const int Gsh = lvl1 ? 5 : 6;
    const float sxy     = lvl1 ? 1.1f : 1.2f;
    const float sxy_off = (sxy - 1.0f) * 0.5f;
    const float sf      = lvl1 ? 16.0f : 8.0f;
    const float aw0 = lvl1 ? 30.f : 10.f, aw1v = lvl1 ? 62.f : 16.f, aw2v = lvl1 ? 59.f : 33.f;
    const float ah0 = lvl1 ? 61.f : 13.f, ah1v = lvl1 ? 45.f : 30.f, ah2v = lvl1 ? 119.f : 23.f;

    const int tloc = lvl1 ? (mtile - 256) : mtile;
    const int b  = tloc >> (lvl1 ? 3 : 5);
    const int p0 = (tloc & ((lvl1 ? 8 : 32) - 1)) * 128;
    const int n0 = ntile * 128;

    const unsigned short* __restrict__ Xp = Xb + ((size_t)b * GG + p0) * C;

    const int tid  = threadIdx.x;
    const int lane = tid & 63;
    const int wid  = tid >> 6;
    const int wm = wid >> 1, wn = wid & 1;

    f32x4 acc[4][4];
    #pragma unroll
    for (int i = 0; i < 4; ++i)
        #pragma unroll
        for (int j = 0; j < 4; ++j)
            acc[i][j] = f32x4{0.f, 0.f, 0.f, 0.f};

    // staging geometry (per thread, loop-invariant):
    // issue i: LDS chunk (i*4+wid)*1024 bytes; lane covers chunk + lane*16
    int rowA[4], scolE[4];  // scolE = swizzled column in ELEMENTS
    #pragma unroll
    for (int i = 0; i < 4; ++i) {
        const int off = ((i * 4 + wid) << 10) + (lane << 4);  // byte offset in 16KB tile
        const int row = off >> 7;
        const int col = off & 127;
        rowA[i]  = row;
        scolE[i] = (col ^ ((row & 7) << 4)) >> 1;
    }

    const int lr = lane & 15;
    const int kqb = (lane >> 4) << 4;          // k-quarter byte offset within 64B half-row
    const int swzR = (lr & 7) << 4;            // read-side XOR (row&7 == lr&7 here)

    const int KT = C >> 6;
    for (int kt = 0; kt < KT; ++kt) {
        const int k0 = kt << 6;
        #pragma unroll
        for (int i = 0; i < 4; ++i) {
            const int chunk = ((i * 4 + wid) << 10);
            // A: pixels all valid
            gload16(Xp + (size_t)rowA[i] * C + k0 + scolE[i], (char*)sA + chunk);
            // B: clamp OOB rows (epilogue masks those channels)
            int grow = n0 + rowA[i];
            grow = grow > (OUT_CH - 1) ? (OUT_CH - 1) : grow;
            gload16(Wb + (size_t)grow * C + k0 + scolE[i], (char*)sB + chunk);
        }
        __syncthreads();   // compiler inserts vmcnt(0) drain before barrier
        #pragma unroll
        for (int kk = 0; kk < 2; ++kk) {
            const int cb = (kk << 6) + kqb;
            short8 af[4], bfr[4];
            #pragma unroll
            for (int i = 0; i < 4; ++i) {
                const int ra = wm * 64 + i * 16 + lr;
                af[i]  = *(const short8*)((const char*)sA + ra * 128 + (cb ^ swzR));
                const int rb = wn * 64 + i * 16 + lr;
                bfr[i] = *(const short8*)((const char*)sB + rb * 128 + (cb ^ swzR));
            }
            #pragma unroll
            for (int i = 0; i < 4; ++i)
                #pragma unroll
                for (int j = 0; j < 4; ++j)
                    acc[i][j] = __builtin_amdgcn_mfma_f32_16x16x32_bf16(af[i], bfr[j], acc[i][j], 0, 0, 0);
        }
        __syncthreads();
    }

    // ---- epilogue: bias + decode + scatter ----
    // C/D layout: col(N)=lane&15, row(M)=(lane>>4)*4+reg
    const int rq = (lane >> 4) * 4;
    const int lvloff = lvl1 ? 73728 : 0;
    #pragma unroll
    for (int j = 0; j < 4; ++j) {
        const int o = n0 + wn * 64 + j * 16 + lr;
        if (o >= OUT_CH) continue;
        const int a  = o / NCHN;
        const int ch = o - a * NCHN;
        const float bv = bias[o];
        const int shp  = a / 6;
        const int angi = a - shp * 6;
        const float aw = (shp == 0) ? aw0 : (shp == 1) ? aw1v : aw2v;
        const float ah = (shp == 0) ? ah0 : (shp == 1) ? ah1v : ah2v;
        const float aa = (angi == 0) ? -1.04719755119659775f :
                         (angi == 1) ? -0.52359877559829887f :
                         (angi == 2) ?  0.0f :
                         (angi == 3) ?  0.52359877559829887f :
                         (angi == 4) ?  1.04719755119659775f :
                                        1.57079632679489662f;
        const size_t obase = (size_t)b * BPB + ((size_t)(lvloff + a * GG)) * NCHN + ch;
        #pragma unroll
        for (int i = 0; i < 4; ++i) {
            #pragma unroll
            for (int r = 0; r < 4; ++r) {
                const int p = p0 + wm * 64 + i * 16 + rq + r;
                const float vv = acc[i][j][r] + bv;
                float res;
                if (ch == 0)      res = (sigm(vv) * sxy - sxy_off + (float)(p & ((1 << Gsh) - 1))) * sf;
                else if (ch == 1) res = (sigm(vv) * sxy - sxy_off + (float)(p >> Gsh)) * sf;
                else if (ch == 2) res = __expf(vv) * aw;
                else if (ch == 3) res = __expf(vv) * ah;
                else if (ch == 4) res = vv + aa;
                else              res = sigm(vv);
                out[obase + (size_t)p * NCHN] = res;
            }
        }
    }
}

// ---------------- fallback (R1 kernel, used only if ws too small) ----------------

__global__ __launch_bounds__(256, 1) void detect_fused(
    const float* __restrict__ x0, const float* __restrict__ x1,
    const float* __restrict__ W0, const float* __restrict__ b0,
    const float* __restrict__ W1, const float* __restrict__ b1,
    float* __restrict__ out)
{
    constexpr int BM = 128, BN = 128, BK = 32;
    __shared__ unsigned short sA[BM][BK + 8];
    __shared__ unsigned short sB[BN][BK + 8];

    const int mtile = blockIdx.x;
    const bool lvl1 = (mtile >= 256);
    const float* __restrict__ X    = lvl1 ? x1 : x0;
    const float* __restrict__ W    = lvl1 ? W1 : W0;
    const float* __restrict__ bias = lvl1 ? b1 : b0;
    const int C   = lvl1 ? 512 : 256;
    const int GG  = lvl1 ? 1024 : 4096;
    const int Gsh = lvl1 ? 5 : 6;
    const float sxy     = lvl1 ? 1.1f : 1.2f;
    const float sxy_off = (sxy - 1.0f) * 0.5f;
    const float sf      = lvl1 ? 16.0f : 8.0f;
    const float aw0 = lvl1 ? 30.f : 10.f, aw1v = lvl1 ? 62.f : 16.f, aw2v = lvl1 ? 59.f : 33.f;
    const float ah0 = lvl1 ? 61.f : 13.f, ah1v = lvl1 ? 45.f : 30.f, ah2v = lvl1 ? 119.f : 23.f;

    const int tloc = lvl1 ? (mtile - 256) : mtile;
    const int b  = tloc >> (lvl1 ? 3 : 5);
    const int p0 = (tloc & ((lvl1 ? 8 : 32) - 1)) * BM;
    const int n0 = blockIdx.y * BN;

    const int tid  = threadIdx.x;
    const int lane = tid & 63;
    const int wid  = tid >> 6;
    const int wm = wid >> 1, wn = wid & 1;

    f32x4 acc[4][4];
    #pragma unroll
    for (int i = 0; i < 4; ++i)
        #pragma unroll
        for (int j = 0; j < 4; ++j)
            acc[i][j] = f32x4{0.f, 0.f, 0.f, 0.f};

    const int am  = tid & 127;
    const int akg = tid >> 7;
    const int bn_ = tid >> 3;
    const int bkq = tid & 7;

    const int KT = C / BK;
    for (int kt = 0; kt < KT; ++kt) {
        const int k0 = kt * BK;
        {
            short8 pk0, pk1;
            #pragma unroll
            for (int kk = 0; kk < 8; ++kk)
                pk0[kk] = (short)f2bf(X[(size_t)(b * C + k0 + akg * 16 + kk) * GG + p0 + am]);
            #pragma unroll
            for (int kk = 0; kk < 8; ++kk)
                pk1[kk] = (short)f2bf(X[(size_t)(b * C + k0 + akg * 16 + 8 + kk) * GG + p0 + am]);
            *(short8*)&sA[am][akg * 16]     = pk0;
            *(short8*)&sA[am][akg * 16 + 8] = pk1;
        }
        #pragma unroll
        for (int pp = 0; pp < 4; ++pp) {
            const int n  = pp * 32 + bn_;
            const int gn = n0 + n;
            short4v pv = short4v{0, 0, 0, 0};
            if (gn < OUT_CH) {
                const float4 f = *(const float4*)&W[(size_t)gn * C + k0 + bkq * 4];
                pv[0] = (short)f2bf(f.x); pv[1] = (short)f2bf(f.y);
                pv[2] = (short)f2bf(f.z); pv[3] = (short)f2bf(f.w);
            }
            *(short4v*)&sB[n][bkq * 4] = pv;
        }
        __syncthreads();
        {
            const int kb = (lane >> 4) * 8;
            const int lr = lane & 15;
            short8 af[4], bf[4];
            #pragma unroll
            for (int i = 0; i < 4; ++i) af[i] = *(const short8*)&sA[wm * 64 + i * 16 + lr][kb];
            #pragma unroll
            for (int j = 0; j < 4; ++j) bf[j] = *(const short8*)&sB[wn * 64 + j * 16 + lr][kb];
            #pragma unroll
            for (int i = 0; i < 4; ++i)
                #pragma unroll
                for (int j = 0; j < 4; ++j)
                    acc[i][j] = __builtin_amdgcn_mfma_f32_16x16x32_bf16(af[i], bf[j], acc[i][j], 0, 0, 0);
        }
        __syncthreads();
    }

    const int lr = lane & 15;
    const int rq = (lane >> 4) * 4;
    const int lvloff = lvl1 ? 73728 : 0;
    #pragma unroll
    for (int j = 0; j < 4; ++j) {
        const int o = n0 + wn * 64 + j * 16 + lr;
        if (o >= OUT_CH) continue;
        const int a  = o / NCHN;
        const int ch = o - a * NCHN;
        const float bv = bias[o];
        const int shp  = a / 6;
        const int angi = a - shp * 6;
        const float aw = (shp == 0) ? aw0 : (shp == 1) ? aw1v : aw2v;
        const float ah = (shp == 0) ? ah0 : (shp == 1) ? ah1v : ah2v;
        const float aa = (angi == 0) ? -1.04719755119659775f :
                         (angi == 1) ? -0.52359877559829887f :
                         (angi == 2) ?  0.0f :
                         (angi == 3) ?  0.52359877559829887f :
                         (angi == 4) ?  1.04719755119659775f :
                                        1.57079632679489662f;
        const size_t obase = (size_t)b * BPB + ((size_t)(lvloff + a * GG)) * NCHN + ch;
        #pragma unroll
        for (int i = 0; i < 4; ++i) {
            #pragma unroll
            for (int r = 0; r < 4; ++r) {
                const int p = p0 + wm * 64 + i * 16 + rq + r;
                const float vv = acc[i][j][r] + bv;
                float res;
                if (ch == 0)      res = (sigm(vv) * sxy - sxy_off + (float)(p & ((1 << Gsh) - 1))) * sf;
                else if (ch == 1) res = (sigm(vv) * sxy - sxy_off + (float)(p >> Gsh)) * sf;
                else if (ch == 2) res = __expf(vv) * aw;
                else if (ch == 3) res = __expf(vv) * ah;
                else if (ch == 4) res = vv + aa;
                else              res = sigm(vv);
                out[obase + (size_t)p * NCHN] = res;
            }
        }
    }
}

extern "C" void kernel_launch(void* const* d_in, const int* in_sizes, int n_in,
                              void* d_out, int out_size, void* d_ws, size_t ws_size,
                              hipStream_t stream) {
    const float* x0 = (const float*)d_in[0];
    const float* x1 = (const float*)d_in[1];
    const float* W0 = (const float*)d_in[2];
    const float* b0 = (const float*)d_in[3];
    const float* W1 = (const float*)d_in[4];
    const float* b1 = (const float*)d_in[5];
    float* out = (float*)d_out;

    // workspace layout (bytes)
    constexpr size_t XB0_OFF = 0;            // 8*4096*256*2  = 16777216
    constexpr size_t XB1_OFF = 16777216;     // 8*1024*512*2  =  8388608
    constexpr size_t WB0_OFF = 25165824;     // 1548*256*2    =   792576
    constexpr size_t WB1_OFF = 25958400;     // 1548*512*2    =  1585152
    constexpr size_t WS_NEEDED = 27543552;

    if (ws_size < WS_NEEDED) {
        // fallback: R1 fused kernel (no workspace)
        dim3 grid(320, 13, 1);
        hipLaunchKernelGGL(detect_fused, grid, dim3(256), 0, stream,
                           x0, x1, W0, b0, W1, b1, out);
        return;
    }

    unsigned short* Xb0 = (unsigned short*)((char*)d_ws + XB0_OFF);
    unsigned short* Xb1 = (unsigned short*)((char*)d_ws + XB1_OFF);
    unsigned short* Wb0 = (unsigned short*)((char*)d_ws + WB0_OFF);
    unsigned short* Wb1 = (unsigned short*)((char*)d_ws + WB1_OFF);

    hipLaunchKernelGGL(conv_w_kernel, dim3((99072 + 255) / 256), dim3(256), 0, stream,
                       W0, Wb0, 99072);
    hipLaunchKernelGGL(conv_w_kernel, dim3((198144 + 255) / 256), dim3(256), 0, stream,
                       W1, Wb1, 198144);
    hipLaunchKernelGGL(transpose_x_kernel, dim3(64, 4, 8), dim3(256), 0, stream,
                       x0, Xb0, 256, 4096);
    hipLaunchKernelGGL(transpose_x_kernel, dim3(16, 8, 8), dim3(256), 0, stream,
                       x1, Xb1, 512, 1024);

    hipLaunchKernelGGL(detect_gemm, dim3(4160), dim3(256), 0, stream,
                       Xb0, Xb1, Wb0, Wb1, b0, b1, out);
}